// Round 3
// baseline (172.392 us; speedup 1.0000x reference)
//
#include <hip/hip_runtime.h>

// B=4, S=4096, d_model=256, d_k=d_v=64
#define B_    4
#define S_    4096
#define DM    256
#define DK    64
#define NROWS (B_ * S_)        // 16384
#define LOG2E 1.4426950408889634f
// log2(1 + 2^-9): folded into the QK MFMA C-operand so that v_perm truncation
// of P becomes round-half-up; scale alpha cancels in num/den.
#define PACK_BIAS 0.0028151295f

typedef __attribute__((ext_vector_type(8))) short bfrag;   // 8 bf16 (4 VGPRs)
typedef __attribute__((ext_vector_type(4))) float ffrag;   // 4 f32 acc

// f32 -> bf16 round-to-nearest-even (prep-path only, not hot)
__device__ __forceinline__ unsigned bf16_rne_hi(float x) {
    unsigned u = __float_as_uint(x);
    return u + 0x7fffu + ((u >> 16) & 1u);
}
__device__ __forceinline__ unsigned short f2bf(float x) {
    return (unsigned short)(bf16_rne_hi(x) >> 16);
}
__device__ __forceinline__ unsigned pack_bf16x2(float lo, float hi) {
    return (bf16_rne_hi(hi) & 0xffff0000u) | (bf16_rne_hi(lo) >> 16);
}

// raw v_exp_f32 (scores bounded: no overflow guards needed)
__device__ __forceinline__ float fast_exp2(float x) {
#if __has_builtin(__builtin_amdgcn_exp2f)
    return __builtin_amdgcn_exp2f(x);
#else
    float r;
    asm("v_exp_f32 %0, %1\n\ts_nop 1" : "=v"(r) : "v"(x));
    return r;
#endif
}

// truncation-pack of two f32 into bf16x2 (1 VALU); inputs pre-scaled by
// (1+2^-9) via the MFMA C bias -> effective round-half-up.
__device__ __forceinline__ unsigned trunc_pack_bf16x2(float lo, float hi) {
    return __builtin_amdgcn_perm(__float_as_uint(hi), __float_as_uint(lo),
                                 0x07060302u);
}

// ---------------------------------------------------------------------------
// Fused prep + projection, one launch (768 blocks):
//   blocks 0..255  : vT transpose+permute
//   blocks 256..767: qp/kp = bf16(relu(x.w^T)*scale) via MFMA; x loads
//                    issued before w-staging (hide HBM latency under staging)
// ---------------------------------------------------------------------------
__device__ __forceinline__ void proj_step(
    const float4 xv0, const float4 xv1, const unsigned short* wlds,
    int kf, int m, int quad, ffrag acc[4])
{
    union { bfrag v; unsigned u[4]; } pk;
    pk.u[0] = pack_bf16x2(xv0.x, xv0.y);
    pk.u[1] = pack_bf16x2(xv0.z, xv0.w);
    pk.u[2] = pack_bf16x2(xv1.x, xv1.y);
    pk.u[3] = pack_bf16x2(xv1.z, xv1.w);
#pragma unroll
    for (int dt = 0; dt < 4; ++dt) {
        const bfrag Bf = *(const bfrag*)&wlds[(dt * 16 + m) * 264 + kf * 32 + quad * 8];
        acc[dt] = __builtin_amdgcn_mfma_f32_16x16x32_bf16(pk.v, Bf, acc[dt], 0, 0, 0);
    }
}

__global__ __launch_bounds__(256) void fused_prep(
    const float* __restrict__ q, const float* __restrict__ k,
    const float* __restrict__ v, const float* __restrict__ wq,
    const float* __restrict__ wk, unsigned short* __restrict__ vT,
    unsigned short* __restrict__ qpb, unsigned short* __restrict__ kpb)
{
    __shared__ __align__(16) char smem[64 * 264 * 2];   // 33792 B (union)
    const int blk  = blockIdx.x;
    const int tid  = threadIdx.x;
    const int lane = tid & 63, w = tid >> 6;

    if (blk < 256) {
        // ---- vT transpose + permute ----
        float (*tile)[65] = (float(*)[65])smem;
        const int b = blk >> 6, s0 = (blk & 63) * 64;
#pragma unroll
        for (int i = 0; i < 16; ++i) {
            const int sl = i * 4 + w;
            tile[sl][lane] = v[(b * S_ + s0 + sl) * DK + lane];
        }
        __syncthreads();
        const int t32 = lane >> 5, pos = lane & 31;
        const int keyl = t32 * 32 + ((pos & 1) ? (pos >> 1) + 16 : (pos >> 1));
#pragma unroll
        for (int i = 0; i < 16; ++i) {
            const int d = i * 4 + w;
            vT[((size_t)(b * 128 + (s0 >> 5) + t32) * 64 + d) * 32 + pos] =
                f2bf(tile[keyl][d]);
        }
    } else {
        // ---- projection: 64 rows/block, wave = 16 rows ----
        unsigned short* wlds = (unsigned short*)smem;   // [64][264] bf16
        const int pb = blk - 256;                       // 0..511
        const int half = pb >> 8, rblk = pb & 255;
        const float* x;
        const float* wsrc;
        unsigned short* o;
        float scale;
        if (half == 0) { x = q; wsrc = wq; o = qpb; scale = 0.125f * LOG2E; }
        else           { x = k; wsrc = wk; o = kpb; scale = 1.0f; }

        const int m = lane & 15, quad = lane >> 4;
        const int rows0 = rblk * 64 + w * 16;
        const float* xrow = x + (size_t)(rows0 + m) * DM + quad * 8;
        const float4* xf4 = (const float4*)xrow;

        // issue first-half x loads NOW (land during w staging + barrier)
        float4 xA[4][2];
#pragma unroll
        for (int t = 0; t < 4; ++t) {
            xA[t][0] = xf4[t * 8];
            xA[t][1] = xf4[t * 8 + 1];
        }

        // stage w (64x256 f32 -> bf16 LDS, stride 264)
#pragma unroll
        for (int i = 0; i < 16; ++i) {
            const int idx4 = i * 256 + tid;             // float4 index, < 4096
            const int r = idx4 >> 6, c4 = idx4 & 63;
            const float4 wv = ((const float4*)wsrc)[idx4];
            uint2 pk;
            pk.x = pack_bf16x2(wv.x, wv.y);
            pk.y = pack_bf16x2(wv.z, wv.w);
            *(uint2*)&wlds[r * 264 + c4 * 4] = pk;
        }
        __syncthreads();

        ffrag acc[4];
#pragma unroll
        for (int dt = 0; dt < 4; ++dt) acc[dt] = (ffrag)(0.0f);

        // consume first half while issuing second half (4 chunks of slack)
        float4 xB[4][2];
#pragma unroll
        for (int kf = 0; kf < 4; ++kf) {
            xB[kf][0] = xf4[(kf + 4) * 8];
            xB[kf][1] = xf4[(kf + 4) * 8 + 1];
            proj_step(xA[kf][0], xA[kf][1], wlds, kf, m, quad, acc);
        }
#pragma unroll
        for (int kf = 0; kf < 4; ++kf)
            proj_step(xB[kf][0], xB[kf][1], wlds, kf + 4, m, quad, acc);

#pragma unroll
        for (int dt = 0; dt < 4; ++dt)
#pragma unroll
            for (int r = 0; r < 4; ++r)
                o[(rows0 + quad * 4 + r) * DK + dt * 16 + m] =
                    f2bf(fmaxf(acc[dt][r], 0.0f) * scale);
    }
}

// ---------------------------------------------------------------------------
// Attention. R3: K triple-buffered (prefetch distance 2 -> ~2.3 loop bodies
// of vmcnt slack on the critical QK edge, vs 1.3 before); V stays ping-pong
// (slack 1.8). Body reordered QK(jj) -> PV(jj-1) -> V-prefetch so the LDS
// P-read gains QK's issue block of slack. Loop fully unrolled: %3 slot
// indices compile-time (no scratch). XCD-chunked swizzle kept from R1.
// ---------------------------------------------------------------------------
__global__ __launch_bounds__(256) void attn_mfma(
    const unsigned short* __restrict__ qp, const unsigned short* __restrict__ kp,
    const unsigned short* __restrict__ vT, float* __restrict__ num_part,
    float* __restrict__ den_part)
{
    __shared__ __align__(16) char smem[20480];   // P buffers (10240) U epilogue red
    unsigned short* Plds = (unsigned short*)smem;   // [4][32*40]
    float* red0 = (float*)smem;                      // epilogue: [2][2560]
    float* red1 = (float*)smem + 2560;

    const int lane = threadIdx.x & 63, w = threadIdx.x >> 6;
    const int m = lane & 15, quad = lane >> 4;

    // XCD-chunked bijective remap (1024 % 8 == 0)
    const int flat = blockIdx.x;                  // 0..1023
    const int wid  = ((flat & 7) << 7) | (flat >> 3);
    const int gy   = wid & 1;                     // key-half
    const int qg   = wid >> 1;                    // 0..511 query group

    const int qbase = qg * 32;
    const int b = qg >> 7;
    const int kstart = (gy * 4 + w) * 512;

    bfrag qa[2][2];
#pragma unroll
    for (int mt = 0; mt < 2; ++mt)
#pragma unroll
        for (int kf = 0; kf < 2; ++kf)
            qa[mt][kf] = *(const bfrag*)&qp[(qbase + mt * 16 + m) * DK + kf * 32 + quad * 8];

    ffrag oacc[2][4];
    float dacc[2][4];
#pragma unroll
    for (int mt = 0; mt < 2; ++mt) {
#pragma unroll
        for (int dt = 0; dt < 4; ++dt) oacc[mt][dt] = (ffrag)(0.0f);
#pragma unroll
        for (int r = 0; r < 4; ++r) dacc[mt][r] = 0.0f;
    }

    // stepped base pointers; all per-tile offsets are 13-bit imm-able
    const unsigned short* kptr = kp + ((size_t)b * S_ + kstart + m) * DK + quad * 8;
    const unsigned short* vptr = vT + ((size_t)(b * 128 + (kstart >> 5)) * 64 + m) * 32 + quad * 8;
    unsigned short* Pw = Plds + w * 1280;

    const ffrag cbias = (ffrag)(PACK_BIAS);

    // K: 3 slots, prefetch distance 2. V: 2 slots, distance 1.
    bfrag kbuf[3][2][2], vbuf[2][4];
#pragma unroll
    for (int s = 0; s < 2; ++s) {
        const unsigned short* kn = kptr + s * 2048;
#pragma unroll
        for (int kt = 0; kt < 2; ++kt)
#pragma unroll
            for (int kf = 0; kf < 2; ++kf)
                kbuf[s][kt][kf] = *(const bfrag*)(kn + kt * 1024 + kf * 32);
#pragma unroll
        for (int dt = 0; dt < 4; ++dt)
            vbuf[s][dt] = *(const bfrag*)(vptr + s * 2048 + dt * 512);
    }

    bfrag pa0, pa1;

#pragma unroll
    for (int jj = 0; jj < 16; ++jj) {
        const int p = jj & 1;
        const int ks  = jj % 3;            // compile-time (full unroll)
        const int ks2 = (jj + 2) % 3;

        // 1) prefetch K(jj+2) -> kbuf[(jj+2)%3]
        if (jj < 14) {
            const unsigned short* kn = kptr + (jj + 2) * 2048;
#pragma unroll
            for (int kt = 0; kt < 2; ++kt)
#pragma unroll
                for (int kf = 0; kf < 2; ++kf)
                    kbuf[ks2][kt][kf] = *(const bfrag*)(kn + kt * 1024 + kf * 32);
        }

        // 2) QK(jj) on kbuf[jj%3]; C seeded with pack bias
        ffrag s[2][2];
#pragma unroll
        for (int mt = 0; mt < 2; ++mt)
#pragma unroll
            for (int kt = 0; kt < 2; ++kt) {
                ffrag t = __builtin_amdgcn_mfma_f32_16x16x32_bf16(qa[mt][0], kbuf[ks][kt][0], cbias, 0, 0, 0);
                s[mt][kt] = __builtin_amdgcn_mfma_f32_16x16x32_bf16(qa[mt][1], kbuf[ks][kt][1], t, 0, 0, 0);
            }

        // 3) PV(jj-1): pa x V(jj-1) in vbuf[p^1] (dies here)
        if (jj > 0) {
#pragma unroll
            for (int dt = 0; dt < 4; ++dt) {
                oacc[0][dt] = __builtin_amdgcn_mfma_f32_16x16x32_bf16(pa0, vbuf[p ^ 1][dt], oacc[0][dt], 0, 0, 0);
                oacc[1][dt] = __builtin_amdgcn_mfma_f32_16x16x32_bf16(pa1, vbuf[p ^ 1][dt], oacc[1][dt], 0, 0, 0);
            }
        }

        // 4) prefetch V(jj+1) -> vbuf[p^1] (slot just freed)
        if (jj < 15) {
            const unsigned short* vn = vptr + (jj + 1) * 2048;
#pragma unroll
            for (int dt = 0; dt < 4; ++dt)
                vbuf[p ^ 1][dt] = *(const bfrag*)(vn + dt * 512);
        }

        // 5) exp (v_exp_f32), mask col 0, den, trunc-pack pairs -> LDS
        const bool mask0 = (jj == 0) && (kstart == 0) && (m == 0);
#pragma unroll
        for (int mt = 0; mt < 2; ++mt)
#pragma unroll
            for (int r = 0; r < 4; ++r) {
                float e0 = fast_exp2(s[mt][0][r]);
                float e1 = fast_exp2(s[mt][1][r]);
                if (mask0) e0 = 0.0f;
                dacc[mt][r] += e0 + e1;
                *(unsigned*)&Pw[(mt * 16 + quad * 4 + r) * 40 + m * 2] =
                    trunc_pack_bf16x2(e0, e1);
            }

        // 6) read P(jj) as A-frags (per-wave DS in-order)
        pa0 = *(const bfrag*)&Pw[(m) * 40 + quad * 8];
        pa1 = *(const bfrag*)&Pw[(16 + m) * 40 + quad * 8];
    }
    // final PV (tile 15): V(15) is in vbuf[1]
#pragma unroll
    for (int dt = 0; dt < 4; ++dt) {
        oacc[0][dt] = __builtin_amdgcn_mfma_f32_16x16x32_bf16(pa0, vbuf[1][dt], oacc[0][dt], 0, 0, 0);
        oacc[1][dt] = __builtin_amdgcn_mfma_f32_16x16x32_bf16(pa1, vbuf[1][dt], oacc[1][dt], 0, 0, 0);
    }

    // den: reduce over the 16 key-lanes within each quad group
#pragma unroll
    for (int mt = 0; mt < 2; ++mt)
#pragma unroll
        for (int r = 0; r < 4; ++r) {
            float d = dacc[mt][r];
            d += __shfl_xor(d, 1, 64);
            d += __shfl_xor(d, 2, 64);
            d += __shfl_xor(d, 4, 64);
            d += __shfl_xor(d, 8, 64);
            dacc[mt][r] = d;
        }

    // cross-wave tree reduce (reuses P LDS; P is dead)
    __syncthreads();
    float* red[2] = { red0, red1 };
    if (w >= 2) {
#pragma unroll
        for (int mt = 0; mt < 2; ++mt) {
#pragma unroll
            for (int dt = 0; dt < 4; ++dt)
#pragma unroll
                for (int r = 0; r < 4; ++r)
                    red[w - 2][((mt * 4 + dt) * 4 + r) * 64 + lane] = oacc[mt][dt][r];
#pragma unroll
            for (int r = 0; r < 4; ++r)
                red[w - 2][2048 + (mt * 4 + r) * 64 + lane] = dacc[mt][r];
        }
    }
    __syncthreads();
    if (w < 2) {
#pragma unroll
        for (int mt = 0; mt < 2; ++mt) {
#pragma unroll
            for (int dt = 0; dt < 4; ++dt)
#pragma unroll
                for (int r = 0; r < 4; ++r)
                    oacc[mt][dt][r] += red[w][((mt * 4 + dt) * 4 + r) * 64 + lane];
#pragma unroll
            for (int r = 0; r < 4; ++r)
                dacc[mt][r] += red[w][2048 + (mt * 4 + r) * 64 + lane];
        }
    }
    __syncthreads();
    if (w == 1) {
#pragma unroll
        for (int mt = 0; mt < 2; ++mt) {
#pragma unroll
            for (int dt = 0; dt < 4; ++dt)
#pragma unroll
                for (int r = 0; r < 4; ++r)
                    red0[((mt * 4 + dt) * 4 + r) * 64 + lane] = oacc[mt][dt][r];
#pragma unroll
            for (int r = 0; r < 4; ++r)
                red0[2048 + (mt * 4 + r) * 64 + lane] = dacc[mt][r];
        }
    }
    __syncthreads();
    if (w == 0) {
#pragma unroll
        for (int mt = 0; mt < 2; ++mt) {
#pragma unroll
            for (int dt = 0; dt < 4; ++dt)
#pragma unroll
                for (int r = 0; r < 4; ++r) {
                    const float nv = oacc[mt][dt][r] + red0[((mt * 4 + dt) * 4 + r) * 64 + lane];
                    num_part[(size_t)gy * NROWS * DK +
                             (qbase + mt * 16 + quad * 4 + r) * DK + dt * 16 + m] = nv;
                }
#pragma unroll
            for (int r = 0; r < 4; ++r) {
                const float dv = dacc[mt][r] + red0[2048 + (mt * 4 + r) * 64 + lane];
                if (m == 0)
                    den_part[gy * NROWS + qbase + mt * 16 + quad * 4 + r] = dv;
            }
        }
    }
}

// ---------------------------------------------------------------------------
__global__ __launch_bounds__(256) void finalize_kernel(
    const float* __restrict__ num_part, const float* __restrict__ den_part,
    float* __restrict__ out)
{
    const int i4 = blockIdx.x * 256 + threadIdx.x;   // float4 index, < 262144
    const int row = i4 >> 4;
    const float4 a = ((const float4*)num_part)[i4];
    const float4 c = ((const float4*)(num_part + (size_t)NROWS * DK))[i4];
    const float inv = 1.0f / (den_part[row] + den_part[NROWS + row]);
    float4 o;
    o.x = (a.x + c.x) * inv;
    o.y = (a.y + c.y) * inv;
    o.z = (a.z + c.z) * inv;
    o.w = (a.w + c.w) * inv;
    ((float4*)out)[i4] = o;
}

// ---------------------------------------------------------------------------
extern "C" void kernel_launch(void* const* d_in, const int* in_sizes, int n_in,
                              void* d_out, int out_size, void* d_ws, size_t ws_size,
                              hipStream_t stream)
{
    const float* q  = (const float*)d_in[0];
    const float* k  = (const float*)d_in[1];
    const float* v  = (const float*)d_in[2];
    const float* wq = (const float*)d_in[3];
    const float* wk = (const float*)d_in[4];
    float* out = (float*)d_out;

    // ws: qpb 2M | kpb 2M | vT 2M | num_part 8M | den_part 128K
    char* p = (char*)d_ws;
    unsigned short* qpb = (unsigned short*)p;   p += (size_t)NROWS * DK * 2;
    unsigned short* kpb = (unsigned short*)p;   p += (size_t)NROWS * DK * 2;
    unsigned short* vT  = (unsigned short*)p;   p += (size_t)B_ * DK * S_ * 2;
    float* num_part     = (float*)p;            p += (size_t)2 * NROWS * DK * 4;
    float* den_part     = (float*)p;

    fused_prep<<<768, 256, 0, stream>>>(q, k, v, wq, wk, vT, qpb, kpb);
    attn_mfma<<<1024, 256, 0, stream>>>(qpb, kpb, vT, num_part, den_part);
    finalize_kernel<<<NROWS * DK / 4 / 256, 256, 0, stream>>>(num_part, den_part, out);
}

// Round 4
// 141.196 us; speedup vs baseline: 1.2209x; 1.2209x over previous
//
#include <hip/hip_runtime.h>

// B=4, S=4096, d_model=256, d_k=d_v=64
#define B_    4
#define S_    4096
#define DM    256
#define DK    64
#define NROWS (B_ * S_)        // 16384
#define NPART 4                // key-split partials
#define LOG2E 1.4426950408889634f
// log2(1 + 2^-9): folded into the QK MFMA C-operand so that v_perm truncation
// of P becomes round-half-up; scale alpha cancels in num/den.
#define PACK_BIAS 0.0028151295f

typedef __attribute__((ext_vector_type(8))) short bfrag;   // 8 bf16 (4 VGPRs)
typedef __attribute__((ext_vector_type(4))) float ffrag;   // 4 f32 acc

// f32 -> bf16 round-to-nearest-even (prep-path only, not hot)
__device__ __forceinline__ unsigned bf16_rne_hi(float x) {
    unsigned u = __float_as_uint(x);
    return u + 0x7fffu + ((u >> 16) & 1u);
}
__device__ __forceinline__ unsigned short f2bf(float x) {
    return (unsigned short)(bf16_rne_hi(x) >> 16);
}
__device__ __forceinline__ unsigned pack_bf16x2(float lo, float hi) {
    return (bf16_rne_hi(hi) & 0xffff0000u) | (bf16_rne_hi(lo) >> 16);
}

// raw v_exp_f32 (scores bounded: no overflow guards needed)
__device__ __forceinline__ float fast_exp2(float x) {
#if __has_builtin(__builtin_amdgcn_exp2f)
    return __builtin_amdgcn_exp2f(x);
#else
    float r;
    asm("v_exp_f32 %0, %1\n\ts_nop 1" : "=v"(r) : "v"(x));
    return r;
#endif
}

// truncation-pack of two f32 into bf16x2 (1 VALU); inputs pre-scaled by
// (1+2^-9) via the MFMA C bias -> effective round-half-up.
__device__ __forceinline__ unsigned trunc_pack_bf16x2(float lo, float hi) {
    return __builtin_amdgcn_perm(__float_as_uint(hi), __float_as_uint(lo),
                                 0x07060302u);
}

// ---------------------------------------------------------------------------
// Fused prep + projection, one launch (768 blocks):
//   blocks 0..255  : vT transpose+permute
//   blocks 256..767: qp/kp = bf16(relu(x.w^T)*scale) via MFMA; x loads
//                    issued before w-staging (hide HBM latency under staging)
// ---------------------------------------------------------------------------
__device__ __forceinline__ void proj_step(
    const float4 xv0, const float4 xv1, const unsigned short* wlds,
    int kf, int m, int quad, ffrag acc[4])
{
    union { bfrag v; unsigned u[4]; } pk;
    pk.u[0] = pack_bf16x2(xv0.x, xv0.y);
    pk.u[1] = pack_bf16x2(xv0.z, xv0.w);
    pk.u[2] = pack_bf16x2(xv1.x, xv1.y);
    pk.u[3] = pack_bf16x2(xv1.z, xv1.w);
#pragma unroll
    for (int dt = 0; dt < 4; ++dt) {
        const bfrag Bf = *(const bfrag*)&wlds[(dt * 16 + m) * 264 + kf * 32 + quad * 8];
        acc[dt] = __builtin_amdgcn_mfma_f32_16x16x32_bf16(pk.v, Bf, acc[dt], 0, 0, 0);
    }
}

__global__ __launch_bounds__(256) void fused_prep(
    const float* __restrict__ q, const float* __restrict__ k,
    const float* __restrict__ v, const float* __restrict__ wq,
    const float* __restrict__ wk, unsigned short* __restrict__ vT,
    unsigned short* __restrict__ qpb, unsigned short* __restrict__ kpb)
{
    __shared__ __align__(16) char smem[64 * 264 * 2];   // 33792 B (union)
    const int blk  = blockIdx.x;
    const int tid  = threadIdx.x;
    const int lane = tid & 63, w = tid >> 6;

    if (blk < 256) {
        // ---- vT transpose + permute ----
        float (*tile)[65] = (float(*)[65])smem;
        const int b = blk >> 6, s0 = (blk & 63) * 64;
#pragma unroll
        for (int i = 0; i < 16; ++i) {
            const int sl = i * 4 + w;
            tile[sl][lane] = v[(b * S_ + s0 + sl) * DK + lane];
        }
        __syncthreads();
        const int t32 = lane >> 5, pos = lane & 31;
        const int keyl = t32 * 32 + ((pos & 1) ? (pos >> 1) + 16 : (pos >> 1));
#pragma unroll
        for (int i = 0; i < 16; ++i) {
            const int d = i * 4 + w;
            vT[((size_t)(b * 128 + (s0 >> 5) + t32) * 64 + d) * 32 + pos] =
                f2bf(tile[keyl][d]);
        }
    } else {
        // ---- projection: 64 rows/block, wave = 16 rows ----
        unsigned short* wlds = (unsigned short*)smem;   // [64][264] bf16
        const int pb = blk - 256;                       // 0..511
        const int half = pb >> 8, rblk = pb & 255;
        const float* x;
        const float* wsrc;
        unsigned short* o;
        float scale;
        if (half == 0) { x = q; wsrc = wq; o = qpb; scale = 0.125f * LOG2E; }
        else           { x = k; wsrc = wk; o = kpb; scale = 1.0f; }

        const int m = lane & 15, quad = lane >> 4;
        const int rows0 = rblk * 64 + w * 16;
        const float* xrow = x + (size_t)(rows0 + m) * DM + quad * 8;
        const float4* xf4 = (const float4*)xrow;

        // issue first-half x loads NOW (land during w staging + barrier)
        float4 xA[4][2];
#pragma unroll
        for (int t = 0; t < 4; ++t) {
            xA[t][0] = xf4[t * 8];
            xA[t][1] = xf4[t * 8 + 1];
        }

        // stage w (64x256 f32 -> bf16 LDS, stride 264)
#pragma unroll
        for (int i = 0; i < 16; ++i) {
            const int idx4 = i * 256 + tid;             // float4 index, < 4096
            const int r = idx4 >> 6, c4 = idx4 & 63;
            const float4 wv = ((const float4*)wsrc)[idx4];
            uint2 pk;
            pk.x = pack_bf16x2(wv.x, wv.y);
            pk.y = pack_bf16x2(wv.z, wv.w);
            *(uint2*)&wlds[r * 264 + c4 * 4] = pk;
        }
        __syncthreads();

        ffrag acc[4];
#pragma unroll
        for (int dt = 0; dt < 4; ++dt) acc[dt] = (ffrag)(0.0f);

        // consume first half while issuing second half (4 chunks of slack)
        float4 xB[4][2];
#pragma unroll
        for (int kf = 0; kf < 4; ++kf) {
            xB[kf][0] = xf4[(kf + 4) * 8];
            xB[kf][1] = xf4[(kf + 4) * 8 + 1];
            proj_step(xA[kf][0], xA[kf][1], wlds, kf, m, quad, acc);
        }
#pragma unroll
        for (int kf = 0; kf < 4; ++kf)
            proj_step(xB[kf][0], xB[kf][1], wlds, kf + 4, m, quad, acc);

#pragma unroll
        for (int dt = 0; dt < 4; ++dt)
#pragma unroll
            for (int r = 0; r < 4; ++r)
                o[(rows0 + quad * 4 + r) * DK + dt * 16 + m] =
                    f2bf(fmaxf(acc[dt][r], 0.0f) * scale);
    }
}

// ---------------------------------------------------------------------------
// Attention. R4: back to R1's ping-pong structure (92 VGPR -> 5 waves/SIMD
// permitted), but keys split 4-way across blocks: 2048 blocks x 4 waves,
// 8 key-tiles (256 keys) per wave. Grid no longer caps residency at 4
// blocks/CU; VGPR permits 5, and 3 queued blocks/CU provide churn to fill
// stall holes + shrink the tail. 4 num/den partials.
// ---------------------------------------------------------------------------
__global__ __launch_bounds__(256) void attn_mfma(
    const unsigned short* __restrict__ qp, const unsigned short* __restrict__ kp,
    const unsigned short* __restrict__ vT, float* __restrict__ num_part,
    float* __restrict__ den_part)
{
    __shared__ __align__(16) char smem[20480];   // P buffers (10240) U epilogue red
    unsigned short* Plds = (unsigned short*)smem;   // [4][32*40]
    float* red0 = (float*)smem;                      // epilogue: [2][2560]
    float* red1 = (float*)smem + 2560;

    const int lane = threadIdx.x & 63, w = threadIdx.x >> 6;
    const int m = lane & 15, quad = lane >> 4;

    // XCD-chunked bijective remap (2048 % 8 == 0, chunk = 256)
    const int flat = blockIdx.x;                  // 0..2047
    const int wid  = ((flat & 7) << 8) | (flat >> 3);
    const int gy   = wid & 3;                     // key quarter (partial id)
    const int qg   = wid >> 2;                    // 0..511 query group

    const int qbase = qg * 32;
    const int b = qg >> 7;
    const int kstart = gy * 1024 + w * 256;       // 8 tiles of 32 keys

    bfrag qa[2][2];
#pragma unroll
    for (int mt = 0; mt < 2; ++mt)
#pragma unroll
        for (int kf = 0; kf < 2; ++kf)
            qa[mt][kf] = *(const bfrag*)&qp[(qbase + mt * 16 + m) * DK + kf * 32 + quad * 8];

    ffrag oacc[2][4];
    float dacc[2][4];
#pragma unroll
    for (int mt = 0; mt < 2; ++mt) {
#pragma unroll
        for (int dt = 0; dt < 4; ++dt) oacc[mt][dt] = (ffrag)(0.0f);
#pragma unroll
        for (int r = 0; r < 4; ++r) dacc[mt][r] = 0.0f;
    }

    // stepped base pointers; all per-tile offsets are 13-bit imm-able
    const unsigned short* kptr = kp + ((size_t)b * S_ + kstart + m) * DK + quad * 8;
    const unsigned short* vptr = vT + ((size_t)(b * 128 + (kstart >> 5)) * 64 + m) * 32 + quad * 8;
    unsigned short* Pw = Plds + w * 1280;

    const ffrag cbias = (ffrag)(PACK_BIAS);

    // preload tile 0 into slot 0
    bfrag kbuf[2][2][2], vbuf[2][4];
#pragma unroll
    for (int kt = 0; kt < 2; ++kt)
#pragma unroll
        for (int kf = 0; kf < 2; ++kf)
            kbuf[0][kt][kf] = *(const bfrag*)(kptr + kt * 1024 + kf * 32);
#pragma unroll
    for (int dt = 0; dt < 4; ++dt)
        vbuf[0][dt] = *(const bfrag*)(vptr + dt * 512);

    bfrag pa0, pa1;

#pragma unroll 2
    for (int jj = 0; jj < 8; ++jj) {
        const int p = jj & 1;

        // 1) prefetch K(jj+1) -> kbuf[p^1]
        if (jj < 7) {
            const unsigned short* kn = kptr + (jj + 1) * 2048;
#pragma unroll
            for (int kt = 0; kt < 2; ++kt)
#pragma unroll
                for (int kf = 0; kf < 2; ++kf)
                    kbuf[p ^ 1][kt][kf] = *(const bfrag*)(kn + kt * 1024 + kf * 32);
        }

        // 2) PV(jj-1): pa + vbuf[p^1] (V(jj-1) dies here)
        if (jj > 0) {
#pragma unroll
            for (int dt = 0; dt < 4; ++dt) {
                oacc[0][dt] = __builtin_amdgcn_mfma_f32_16x16x32_bf16(pa0, vbuf[p ^ 1][dt], oacc[0][dt], 0, 0, 0);
                oacc[1][dt] = __builtin_amdgcn_mfma_f32_16x16x32_bf16(pa1, vbuf[p ^ 1][dt], oacc[1][dt], 0, 0, 0);
            }
        }

        // 3) prefetch V(jj+1) -> vbuf[p^1] (freed slot)
        if (jj < 7) {
            const unsigned short* vn = vptr + (jj + 1) * 2048;
#pragma unroll
            for (int dt = 0; dt < 4; ++dt)
                vbuf[p ^ 1][dt] = *(const bfrag*)(vn + dt * 512);
        }

        // 4) QK(jj) on kbuf[p]; C seeded with pack bias
        ffrag s[2][2];
#pragma unroll
        for (int mt = 0; mt < 2; ++mt)
#pragma unroll
            for (int kt = 0; kt < 2; ++kt) {
                ffrag t = __builtin_amdgcn_mfma_f32_16x16x32_bf16(qa[mt][0], kbuf[p][kt][0], cbias, 0, 0, 0);
                s[mt][kt] = __builtin_amdgcn_mfma_f32_16x16x32_bf16(qa[mt][1], kbuf[p][kt][1], t, 0, 0, 0);
            }

        // 5) exp (v_exp_f32), mask col 0, den, trunc-pack pairs -> LDS
        const bool mask0 = (jj == 0) && (kstart == 0) && (m == 0);
#pragma unroll
        for (int mt = 0; mt < 2; ++mt)
#pragma unroll
            for (int r = 0; r < 4; ++r) {
                float e0 = fast_exp2(s[mt][0][r]);
                float e1 = fast_exp2(s[mt][1][r]);
                if (mask0) e0 = 0.0f;
                dacc[mt][r] += e0 + e1;
                *(unsigned*)&Pw[(mt * 16 + quad * 4 + r) * 40 + m * 2] =
                    trunc_pack_bf16x2(e0, e1);
            }

        // 6) read P(jj) as A-frags (per-wave DS in-order)
        pa0 = *(const bfrag*)&Pw[(m) * 40 + quad * 8];
        pa1 = *(const bfrag*)&Pw[(16 + m) * 40 + quad * 8];
    }
    // final PV (tile 7): V(7) is in vbuf[1] (loop count even)
#pragma unroll
    for (int dt = 0; dt < 4; ++dt) {
        oacc[0][dt] = __builtin_amdgcn_mfma_f32_16x16x32_bf16(pa0, vbuf[1][dt], oacc[0][dt], 0, 0, 0);
        oacc[1][dt] = __builtin_amdgcn_mfma_f32_16x16x32_bf16(pa1, vbuf[1][dt], oacc[1][dt], 0, 0, 0);
    }

    // den: reduce over the 16 key-lanes within each quad group
#pragma unroll
    for (int mt = 0; mt < 2; ++mt)
#pragma unroll
        for (int r = 0; r < 4; ++r) {
            float d = dacc[mt][r];
            d += __shfl_xor(d, 1, 64);
            d += __shfl_xor(d, 2, 64);
            d += __shfl_xor(d, 4, 64);
            d += __shfl_xor(d, 8, 64);
            dacc[mt][r] = d;
        }

    // cross-wave tree reduce (reuses P LDS; P is dead)
    __syncthreads();
    if (w >= 2) {
        float* dst = (w == 2) ? red0 : red1;     // static select, no ptr array
#pragma unroll
        for (int mt = 0; mt < 2; ++mt) {
#pragma unroll
            for (int dt = 0; dt < 4; ++dt)
#pragma unroll
                for (int r = 0; r < 4; ++r)
                    dst[((mt * 4 + dt) * 4 + r) * 64 + lane] = oacc[mt][dt][r];
#pragma unroll
            for (int r = 0; r < 4; ++r)
                dst[2048 + (mt * 4 + r) * 64 + lane] = dacc[mt][r];
        }
    }
    __syncthreads();
    if (w < 2) {
        const float* src = (w == 0) ? red0 : red1;
#pragma unroll
        for (int mt = 0; mt < 2; ++mt) {
#pragma unroll
            for (int dt = 0; dt < 4; ++dt)
#pragma unroll
                for (int r = 0; r < 4; ++r)
                    oacc[mt][dt][r] += src[((mt * 4 + dt) * 4 + r) * 64 + lane];
#pragma unroll
            for (int r = 0; r < 4; ++r)
                dacc[mt][r] += src[2048 + (mt * 4 + r) * 64 + lane];
        }
    }
    __syncthreads();
    if (w == 1) {
#pragma unroll
        for (int mt = 0; mt < 2; ++mt) {
#pragma unroll
            for (int dt = 0; dt < 4; ++dt)
#pragma unroll
                for (int r = 0; r < 4; ++r)
                    red0[((mt * 4 + dt) * 4 + r) * 64 + lane] = oacc[mt][dt][r];
#pragma unroll
            for (int r = 0; r < 4; ++r)
                red0[2048 + (mt * 4 + r) * 64 + lane] = dacc[mt][r];
        }
    }
    __syncthreads();
    if (w == 0) {
#pragma unroll
        for (int mt = 0; mt < 2; ++mt) {
#pragma unroll
            for (int dt = 0; dt < 4; ++dt)
#pragma unroll
                for (int r = 0; r < 4; ++r) {
                    const float nv = oacc[mt][dt][r] + red0[((mt * 4 + dt) * 4 + r) * 64 + lane];
                    num_part[(size_t)gy * NROWS * DK +
                             (qbase + mt * 16 + quad * 4 + r) * DK + dt * 16 + m] = nv;
                }
#pragma unroll
            for (int r = 0; r < 4; ++r) {
                const float dv = dacc[mt][r] + red0[2048 + (mt * 4 + r) * 64 + lane];
                if (m == 0)
                    den_part[gy * NROWS + qbase + mt * 16 + quad * 4 + r] = dv;
            }
        }
    }
}

// ---------------------------------------------------------------------------
__global__ __launch_bounds__(256) void finalize_kernel(
    const float* __restrict__ num_part, const float* __restrict__ den_part,
    float* __restrict__ out)
{
    const int i4 = blockIdx.x * 256 + threadIdx.x;   // float4 index, < 262144
    const int row = i4 >> 4;
    const float4 a0 = ((const float4*)num_part)[i4];
    const float4 a1 = ((const float4*)(num_part + (size_t)NROWS * DK))[i4];
    const float4 a2 = ((const float4*)(num_part + (size_t)2 * NROWS * DK))[i4];
    const float4 a3 = ((const float4*)(num_part + (size_t)3 * NROWS * DK))[i4];
    const float inv = 1.0f / (den_part[row] + den_part[NROWS + row] +
                              den_part[2 * NROWS + row] + den_part[3 * NROWS + row]);
    float4 o;
    o.x = (a0.x + a1.x + a2.x + a3.x) * inv;
    o.y = (a0.y + a1.y + a2.y + a3.y) * inv;
    o.z = (a0.z + a1.z + a2.z + a3.z) * inv;
    o.w = (a0.w + a1.w + a2.w + a3.w) * inv;
    ((float4*)out)[i4] = o;
}

// ---------------------------------------------------------------------------
extern "C" void kernel_launch(void* const* d_in, const int* in_sizes, int n_in,
                              void* d_out, int out_size, void* d_ws, size_t ws_size,
                              hipStream_t stream)
{
    const float* q  = (const float*)d_in[0];
    const float* k  = (const float*)d_in[1];
    const float* v  = (const float*)d_in[2];
    const float* wq = (const float*)d_in[3];
    const float* wk = (const float*)d_in[4];
    float* out = (float*)d_out;

    // ws: qpb 2M | kpb 2M | vT 2M | num_part 16M | den_part 256K  (~22.3 MB)
    char* p = (char*)d_ws;
    unsigned short* qpb = (unsigned short*)p;   p += (size_t)NROWS * DK * 2;
    unsigned short* kpb = (unsigned short*)p;   p += (size_t)NROWS * DK * 2;
    unsigned short* vT  = (unsigned short*)p;   p += (size_t)B_ * DK * S_ * 2;
    float* num_part     = (float*)p;            p += (size_t)NPART * NROWS * DK * 4;
    float* den_part     = (float*)p;

    fused_prep<<<768, 256, 0, stream>>>(q, k, v, wq, wk, vT, qpb, kpb);
    attn_mfma<<<2048, 256, 0, stream>>>(qpb, kpb, vT, num_part, den_part);
    finalize_kernel<<<NROWS * DK / 4 / 256, 256, 0, stream>>>(num_part, den_part, out);
}

// Round 5
// 132.977 us; speedup vs baseline: 1.2964x; 1.0618x over previous
//
#include <hip/hip_runtime.h>

// B=4, S=4096, d_model=256, d_k=d_v=64
#define B_    4
#define S_    4096
#define DM    256
#define DK    64
#define NROWS (B_ * S_)        // 16384
#define LOG2E 1.4426950408889634f
// log2(1 + 2^-9): folded into the QK MFMA C-operand so that v_perm truncation
// of P becomes round-half-up; scale alpha cancels in num/den.
#define PACK_BIAS 0.0028151295f

typedef __attribute__((ext_vector_type(8))) short bfrag;   // 8 bf16 (4 VGPRs)
typedef __attribute__((ext_vector_type(4))) float ffrag;   // 4 f32 acc

// f32 -> bf16 round-to-nearest-even (prep-path only, not hot)
__device__ __forceinline__ unsigned bf16_rne_hi(float x) {
    unsigned u = __float_as_uint(x);
    return u + 0x7fffu + ((u >> 16) & 1u);
}
__device__ __forceinline__ unsigned short f2bf(float x) {
    return (unsigned short)(bf16_rne_hi(x) >> 16);
}
__device__ __forceinline__ unsigned pack_bf16x2(float lo, float hi) {
    return (bf16_rne_hi(hi) & 0xffff0000u) | (bf16_rne_hi(lo) >> 16);
}

// raw v_exp_f32 (scores bounded: no overflow guards needed)
__device__ __forceinline__ float fast_exp2(float x) {
#if __has_builtin(__builtin_amdgcn_exp2f)
    return __builtin_amdgcn_exp2f(x);
#else
    float r;
    asm("v_exp_f32 %0, %1\n\ts_nop 1" : "=v"(r) : "v"(x));
    return r;
#endif
}

// truncation-pack of two f32 into bf16x2 (1 VALU); inputs pre-scaled by
// (1+2^-9) via the MFMA C bias -> effective round-half-up.
__device__ __forceinline__ unsigned trunc_pack_bf16x2(float lo, float hi) {
    return __builtin_amdgcn_perm(__float_as_uint(hi), __float_as_uint(lo),
                                 0x07060302u);
}

// ---------------------------------------------------------------------------
// Fused prep + projection, one launch (768 blocks):
//   blocks 0..255  : vT transpose+permute
//   blocks 256..767: qp/kp = bf16(relu(x.w^T)*scale) via MFMA; x loads
//                    issued before w-staging (hide HBM latency under staging)
// ---------------------------------------------------------------------------
__device__ __forceinline__ void proj_step(
    const float4 xv0, const float4 xv1, const unsigned short* wlds,
    int kf, int m, int quad, ffrag acc[4])
{
    union { bfrag v; unsigned u[4]; } pk;
    pk.u[0] = pack_bf16x2(xv0.x, xv0.y);
    pk.u[1] = pack_bf16x2(xv0.z, xv0.w);
    pk.u[2] = pack_bf16x2(xv1.x, xv1.y);
    pk.u[3] = pack_bf16x2(xv1.z, xv1.w);
#pragma unroll
    for (int dt = 0; dt < 4; ++dt) {
        const bfrag Bf = *(const bfrag*)&wlds[(dt * 16 + m) * 264 + kf * 32 + quad * 8];
        acc[dt] = __builtin_amdgcn_mfma_f32_16x16x32_bf16(pk.v, Bf, acc[dt], 0, 0, 0);
    }
}

__global__ __launch_bounds__(256) void fused_prep(
    const float* __restrict__ q, const float* __restrict__ k,
    const float* __restrict__ v, const float* __restrict__ wq,
    const float* __restrict__ wk, unsigned short* __restrict__ vT,
    unsigned short* __restrict__ qpb, unsigned short* __restrict__ kpb)
{
    __shared__ __align__(16) char smem[64 * 264 * 2];   // 33792 B (union)
    const int blk  = blockIdx.x;
    const int tid  = threadIdx.x;
    const int lane = tid & 63, w = tid >> 6;

    if (blk < 256) {
        // ---- vT transpose + permute ----
        float (*tile)[65] = (float(*)[65])smem;
        const int b = blk >> 6, s0 = (blk & 63) * 64;
#pragma unroll
        for (int i = 0; i < 16; ++i) {
            const int sl = i * 4 + w;
            tile[sl][lane] = v[(b * S_ + s0 + sl) * DK + lane];
        }
        __syncthreads();
        const int t32 = lane >> 5, pos = lane & 31;
        const int keyl = t32 * 32 + ((pos & 1) ? (pos >> 1) + 16 : (pos >> 1));
#pragma unroll
        for (int i = 0; i < 16; ++i) {
            const int d = i * 4 + w;
            vT[((size_t)(b * 128 + (s0 >> 5) + t32) * 64 + d) * 32 + pos] =
                f2bf(tile[keyl][d]);
        }
    } else {
        // ---- projection: 64 rows/block, wave = 16 rows ----
        unsigned short* wlds = (unsigned short*)smem;   // [64][264] bf16
        const int pb = blk - 256;                       // 0..511
        const int half = pb >> 8, rblk = pb & 255;
        const float* x;
        const float* wsrc;
        unsigned short* o;
        float scale;
        if (half == 0) { x = q; wsrc = wq; o = qpb; scale = 0.125f * LOG2E; }
        else           { x = k; wsrc = wk; o = kpb; scale = 1.0f; }

        const int m = lane & 15, quad = lane >> 4;
        const int rows0 = rblk * 64 + w * 16;
        const float* xrow = x + (size_t)(rows0 + m) * DM + quad * 8;
        const float4* xf4 = (const float4*)xrow;

        // issue first-half x loads NOW (land during w staging + barrier)
        float4 xA[4][2];
#pragma unroll
        for (int t = 0; t < 4; ++t) {
            xA[t][0] = xf4[t * 8];
            xA[t][1] = xf4[t * 8 + 1];
        }

        // stage w (64x256 f32 -> bf16 LDS, stride 264)
#pragma unroll
        for (int i = 0; i < 16; ++i) {
            const int idx4 = i * 256 + tid;             // float4 index, < 4096
            const int r = idx4 >> 6, c4 = idx4 & 63;
            const float4 wv = ((const float4*)wsrc)[idx4];
            uint2 pk;
            pk.x = pack_bf16x2(wv.x, wv.y);
            pk.y = pack_bf16x2(wv.z, wv.w);
            *(uint2*)&wlds[r * 264 + c4 * 4] = pk;
        }
        __syncthreads();

        ffrag acc[4];
#pragma unroll
        for (int dt = 0; dt < 4; ++dt) acc[dt] = (ffrag)(0.0f);

        // consume first half while issuing second half (4 chunks of slack)
        float4 xB[4][2];
#pragma unroll
        for (int kf = 0; kf < 4; ++kf) {
            xB[kf][0] = xf4[(kf + 4) * 8];
            xB[kf][1] = xf4[(kf + 4) * 8 + 1];
            proj_step(xA[kf][0], xA[kf][1], wlds, kf, m, quad, acc);
        }
#pragma unroll
        for (int kf = 0; kf < 4; ++kf)
            proj_step(xB[kf][0], xB[kf][1], wlds, kf + 4, m, quad, acc);

#pragma unroll
        for (int dt = 0; dt < 4; ++dt)
#pragma unroll
            for (int r = 0; r < 4; ++r)
                o[(rows0 + quad * 4 + r) * DK + dt * 16 + m] =
                    f2bf(fmaxf(acc[dt][r], 0.0f) * scale);
    }
}

// ---------------------------------------------------------------------------
// Attention. R5: NO key split — 512 blocks x 4 waves; each wave walks 32
// key-tiles (1024 keys). Justified by R4's null (offered blocks beyond
// ~2/CU contribute zero throughput). Each block now holds the complete
// num/den for its 32 rows -> divide in-register, write `out` directly.
// Finalize kernel, its launch gap, and 20.6 MB of partial traffic deleted.
// Ping-pong structure + XCD-chunked swizzle (chunk=64) kept from R1.
// ---------------------------------------------------------------------------
__global__ __launch_bounds__(256) void attn_mfma(
    const unsigned short* __restrict__ qp, const unsigned short* __restrict__ kp,
    const unsigned short* __restrict__ vT, float* __restrict__ out)
{
    __shared__ __align__(16) char smem[20480];   // P buffers (10240) U epilogue red
    unsigned short* Plds = (unsigned short*)smem;   // [4][32*40]
    float* red0 = (float*)smem;                      // epilogue: [2][2560]
    float* red1 = (float*)smem + 2560;

    const int lane = threadIdx.x & 63, w = threadIdx.x >> 6;
    const int m = lane & 15, quad = lane >> 4;

    // XCD-chunked bijective remap (512 % 8 == 0, chunk = 64)
    const int flat = blockIdx.x;                  // 0..511
    const int qg   = ((flat & 7) << 6) | (flat >> 3);   // 0..511 query group

    const int qbase = qg * 32;
    const int b = qg >> 7;
    const int kstart = w * 1024;                  // 32 tiles of 32 keys/wave

    bfrag qa[2][2];
#pragma unroll
    for (int mt = 0; mt < 2; ++mt)
#pragma unroll
        for (int kf = 0; kf < 2; ++kf)
            qa[mt][kf] = *(const bfrag*)&qp[(qbase + mt * 16 + m) * DK + kf * 32 + quad * 8];

    ffrag oacc[2][4];
    float dacc[2][4];
#pragma unroll
    for (int mt = 0; mt < 2; ++mt) {
#pragma unroll
        for (int dt = 0; dt < 4; ++dt) oacc[mt][dt] = (ffrag)(0.0f);
#pragma unroll
        for (int r = 0; r < 4; ++r) dacc[mt][r] = 0.0f;
    }

    // stepped base pointers; all per-tile offsets are 13-bit imm-able
    const unsigned short* kptr = kp + ((size_t)b * S_ + kstart + m) * DK + quad * 8;
    const unsigned short* vptr = vT + ((size_t)(b * 128 + (kstart >> 5)) * 64 + m) * 32 + quad * 8;
    unsigned short* Pw = Plds + w * 1280;

    const ffrag cbias = (ffrag)(PACK_BIAS);

    // preload tile 0 into slot 0
    bfrag kbuf[2][2][2], vbuf[2][4];
#pragma unroll
    for (int kt = 0; kt < 2; ++kt)
#pragma unroll
        for (int kf = 0; kf < 2; ++kf)
            kbuf[0][kt][kf] = *(const bfrag*)(kptr + kt * 1024 + kf * 32);
#pragma unroll
    for (int dt = 0; dt < 4; ++dt)
        vbuf[0][dt] = *(const bfrag*)(vptr + dt * 512);

    bfrag pa0, pa1;

#pragma unroll 2
    for (int jj = 0; jj < 32; ++jj) {
        const int p = jj & 1;

        // 1) prefetch K(jj+1) -> kbuf[p^1]
        if (jj < 31) {
            const unsigned short* kn = kptr + (jj + 1) * 2048;
#pragma unroll
            for (int kt = 0; kt < 2; ++kt)
#pragma unroll
                for (int kf = 0; kf < 2; ++kf)
                    kbuf[p ^ 1][kt][kf] = *(const bfrag*)(kn + kt * 1024 + kf * 32);
        }

        // 2) PV(jj-1): pa + vbuf[p^1] (V(jj-1) dies here)
        if (jj > 0) {
#pragma unroll
            for (int dt = 0; dt < 4; ++dt) {
                oacc[0][dt] = __builtin_amdgcn_mfma_f32_16x16x32_bf16(pa0, vbuf[p ^ 1][dt], oacc[0][dt], 0, 0, 0);
                oacc[1][dt] = __builtin_amdgcn_mfma_f32_16x16x32_bf16(pa1, vbuf[p ^ 1][dt], oacc[1][dt], 0, 0, 0);
            }
        }

        // 3) prefetch V(jj+1) -> vbuf[p^1] (freed slot)
        if (jj < 31) {
            const unsigned short* vn = vptr + (jj + 1) * 2048;
#pragma unroll
            for (int dt = 0; dt < 4; ++dt)
                vbuf[p ^ 1][dt] = *(const bfrag*)(vn + dt * 512);
        }

        // 4) QK(jj) on kbuf[p]; C seeded with pack bias
        ffrag s[2][2];
#pragma unroll
        for (int mt = 0; mt < 2; ++mt)
#pragma unroll
            for (int kt = 0; kt < 2; ++kt) {
                ffrag t = __builtin_amdgcn_mfma_f32_16x16x32_bf16(qa[mt][0], kbuf[p][kt][0], cbias, 0, 0, 0);
                s[mt][kt] = __builtin_amdgcn_mfma_f32_16x16x32_bf16(qa[mt][1], kbuf[p][kt][1], t, 0, 0, 0);
            }

        // 5) exp (v_exp_f32), mask col 0, den, trunc-pack pairs -> LDS
        const bool mask0 = (jj == 0) && (w == 0) && (m == 0);
#pragma unroll
        for (int mt = 0; mt < 2; ++mt)
#pragma unroll
            for (int r = 0; r < 4; ++r) {
                float e0 = fast_exp2(s[mt][0][r]);
                float e1 = fast_exp2(s[mt][1][r]);
                if (mask0) e0 = 0.0f;
                dacc[mt][r] += e0 + e1;
                *(unsigned*)&Pw[(mt * 16 + quad * 4 + r) * 40 + m * 2] =
                    trunc_pack_bf16x2(e0, e1);
            }

        // 6) read P(jj) as A-frags (per-wave DS in-order)
        pa0 = *(const bfrag*)&Pw[(m) * 40 + quad * 8];
        pa1 = *(const bfrag*)&Pw[(16 + m) * 40 + quad * 8];
    }
    // final PV (tile 31): V(31) is in vbuf[1] (loop count even)
#pragma unroll
    for (int dt = 0; dt < 4; ++dt) {
        oacc[0][dt] = __builtin_amdgcn_mfma_f32_16x16x32_bf16(pa0, vbuf[1][dt], oacc[0][dt], 0, 0, 0);
        oacc[1][dt] = __builtin_amdgcn_mfma_f32_16x16x32_bf16(pa1, vbuf[1][dt], oacc[1][dt], 0, 0, 0);
    }

    // den: reduce over the 16 key-lanes within each quad group
#pragma unroll
    for (int mt = 0; mt < 2; ++mt)
#pragma unroll
        for (int r = 0; r < 4; ++r) {
            float d = dacc[mt][r];
            d += __shfl_xor(d, 1, 64);
            d += __shfl_xor(d, 2, 64);
            d += __shfl_xor(d, 4, 64);
            d += __shfl_xor(d, 8, 64);
            dacc[mt][r] = d;
        }

    // cross-wave tree reduce (reuses P LDS; P is dead)
    __syncthreads();
    if (w >= 2) {
        float* dst = (w == 2) ? red0 : red1;     // static select, no ptr array
#pragma unroll
        for (int mt = 0; mt < 2; ++mt) {
#pragma unroll
            for (int dt = 0; dt < 4; ++dt)
#pragma unroll
                for (int r = 0; r < 4; ++r)
                    dst[((mt * 4 + dt) * 4 + r) * 64 + lane] = oacc[mt][dt][r];
#pragma unroll
            for (int r = 0; r < 4; ++r)
                dst[2048 + (mt * 4 + r) * 64 + lane] = dacc[mt][r];
        }
    }
    __syncthreads();
    if (w < 2) {
        const float* src = (w == 0) ? red0 : red1;
#pragma unroll
        for (int mt = 0; mt < 2; ++mt) {
#pragma unroll
            for (int dt = 0; dt < 4; ++dt)
#pragma unroll
                for (int r = 0; r < 4; ++r)
                    oacc[mt][dt][r] += src[((mt * 4 + dt) * 4 + r) * 64 + lane];
#pragma unroll
            for (int r = 0; r < 4; ++r)
                dacc[mt][r] += src[2048 + (mt * 4 + r) * 64 + lane];
        }
    }
    __syncthreads();
    if (w == 1) {
#pragma unroll
        for (int mt = 0; mt < 2; ++mt) {
#pragma unroll
            for (int dt = 0; dt < 4; ++dt)
#pragma unroll
                for (int r = 0; r < 4; ++r)
                    red0[((mt * 4 + dt) * 4 + r) * 64 + lane] = oacc[mt][dt][r];
#pragma unroll
            for (int r = 0; r < 4; ++r)
                red0[2048 + (mt * 4 + r) * 64 + lane] = dacc[mt][r];
        }
    }
    __syncthreads();
    if (w == 0) {
        // complete num/den in-block: divide and write final output
#pragma unroll
        for (int mt = 0; mt < 2; ++mt) {
            float invd[4];
#pragma unroll
            for (int r = 0; r < 4; ++r) {
                const float dv = dacc[mt][r] + red0[2048 + (mt * 4 + r) * 64 + lane];
                invd[r] = 1.0f / dv;
            }
#pragma unroll
            for (int dt = 0; dt < 4; ++dt)
#pragma unroll
                for (int r = 0; r < 4; ++r) {
                    const float nv = oacc[mt][dt][r] + red0[((mt * 4 + dt) * 4 + r) * 64 + lane];
                    out[(size_t)(qbase + mt * 16 + quad * 4 + r) * DK + dt * 16 + m] =
                        nv * invd[r];
                }
        }
    }
}

// ---------------------------------------------------------------------------
extern "C" void kernel_launch(void* const* d_in, const int* in_sizes, int n_in,
                              void* d_out, int out_size, void* d_ws, size_t ws_size,
                              hipStream_t stream)
{
    const float* q  = (const float*)d_in[0];
    const float* k  = (const float*)d_in[1];
    const float* v  = (const float*)d_in[2];
    const float* wq = (const float*)d_in[3];
    const float* wk = (const float*)d_in[4];
    float* out = (float*)d_out;

    // ws: qpb 2M | kpb 2M | vT 2M  (6 MB total; partials deleted)
    char* p = (char*)d_ws;
    unsigned short* qpb = (unsigned short*)p;   p += (size_t)NROWS * DK * 2;
    unsigned short* kpb = (unsigned short*)p;   p += (size_t)NROWS * DK * 2;
    unsigned short* vT  = (unsigned short*)p;

    fused_prep<<<768, 256, 0, stream>>>(q, k, v, wq, wk, vT, qpb, kpb);
    attn_mfma<<<512, 256, 0, stream>>>(qpb, kpb, vT, out);
}

// Round 7
// 115.032 us; speedup vs baseline: 1.4986x; 1.1560x over previous
//
#include <hip/hip_runtime.h>

// B=4, S=4096, d_model=256, d_k=d_v=64
#define B_    4
#define S_    4096
#define DM    256
#define DK    64
#define NROWS (B_ * S_)        // 16384
#define LOG2E 1.4426950408889634f
// log2(1 + 2^-9): folded into the QK MFMA C-operand so that v_perm truncation
// of P becomes round-half-up; scale alpha cancels in num/den.
#define PACK_BIAS 0.0028151295f

typedef __attribute__((ext_vector_type(8))) short bfrag;   // 8 bf16 (4 VGPRs)
typedef __attribute__((ext_vector_type(4))) float ffrag;   // 4 f32 acc

__device__ __forceinline__ unsigned bf16_rne_hi(float x) {
    unsigned u = __float_as_uint(x);
    return u + 0x7fffu + ((u >> 16) & 1u);
}
__device__ __forceinline__ unsigned short f2bf(float x) {
    return (unsigned short)(bf16_rne_hi(x) >> 16);
}
__device__ __forceinline__ unsigned pack_bf16x2(float lo, float hi) {
    return (bf16_rne_hi(hi) & 0xffff0000u) | (bf16_rne_hi(lo) >> 16);
}

// raw v_exp_f32 (scores bounded: no overflow guards needed)
__device__ __forceinline__ float fast_exp2(float x) {
#if __has_builtin(__builtin_amdgcn_exp2f)
    return __builtin_amdgcn_exp2f(x);
#else
    float r;
    asm("v_exp_f32 %0, %1\n\ts_nop 1" : "=v"(r) : "v"(x));
    return r;
#endif
}

// truncation-pack of two f32 into bf16x2 (1 VALU); inputs pre-scaled by
// (1+2^-9) via the MFMA C bias -> effective round-half-up.
__device__ __forceinline__ unsigned trunc_pack_bf16x2(float lo, float hi) {
    return __builtin_amdgcn_perm(__float_as_uint(hi), __float_as_uint(lo),
                                 0x07060302u);
}

// ---------------------------------------------------------------------------
// Fused prep + projection (unchanged from R5 — known good)
// ---------------------------------------------------------------------------
__device__ __forceinline__ void proj_step(
    const float4 xv0, const float4 xv1, const unsigned short* wlds,
    int kf, int m, int quad, ffrag acc[4])
{
    union { bfrag v; unsigned u[4]; } pk;
    pk.u[0] = pack_bf16x2(xv0.x, xv0.y);
    pk.u[1] = pack_bf16x2(xv0.z, xv0.w);
    pk.u[2] = pack_bf16x2(xv1.x, xv1.y);
    pk.u[3] = pack_bf16x2(xv1.z, xv1.w);
#pragma unroll
    for (int dt = 0; dt < 4; ++dt) {
        const bfrag Bf = *(const bfrag*)&wlds[(dt * 16 + m) * 264 + kf * 32 + quad * 8];
        acc[dt] = __builtin_amdgcn_mfma_f32_16x16x32_bf16(pk.v, Bf, acc[dt], 0, 0, 0);
    }
}

__global__ __launch_bounds__(256) void fused_prep(
    const float* __restrict__ q, const float* __restrict__ k,
    const float* __restrict__ v, const float* __restrict__ wq,
    const float* __restrict__ wk, unsigned short* __restrict__ vT,
    unsigned short* __restrict__ qpb, unsigned short* __restrict__ kpb)
{
    __shared__ __align__(16) char smem[64 * 264 * 2];   // 33792 B (union)
    const int blk  = blockIdx.x;
    const int tid  = threadIdx.x;
    const int lane = tid & 63, w = tid >> 6;

    if (blk < 256) {
        // ---- vT transpose + permute ----
        float (*tile)[65] = (float(*)[65])smem;
        const int b = blk >> 6, s0 = (blk & 63) * 64;
#pragma unroll
        for (int i = 0; i < 16; ++i) {
            const int sl = i * 4 + w;
            tile[sl][lane] = v[(b * S_ + s0 + sl) * DK + lane];
        }
        __syncthreads();
        const int t32 = lane >> 5, pos = lane & 31;
        const int keyl = t32 * 32 + ((pos & 1) ? (pos >> 1) + 16 : (pos >> 1));
#pragma unroll
        for (int i = 0; i < 16; ++i) {
            const int d = i * 4 + w;
            vT[((size_t)(b * 128 + (s0 >> 5) + t32) * 64 + d) * 32 + pos] =
                f2bf(tile[keyl][d]);
        }
    } else {
        // ---- projection: 64 rows/block, wave = 16 rows ----
        unsigned short* wlds = (unsigned short*)smem;   // [64][264] bf16
        const int pb = blk - 256;                       // 0..511
        const int half = pb >> 8, rblk = pb & 255;
        const float* x;
        const float* wsrc;
        unsigned short* o;
        float scale;
        if (half == 0) { x = q; wsrc = wq; o = qpb; scale = 0.125f * LOG2E; }
        else           { x = k; wsrc = wk; o = kpb; scale = 1.0f; }

        const int m = lane & 15, quad = lane >> 4;
        const int rows0 = rblk * 64 + w * 16;
        const float* xrow = x + (size_t)(rows0 + m) * DM + quad * 8;
        const float4* xf4 = (const float4*)xrow;

        // issue first-half x loads NOW (land during w staging + barrier)
        float4 xA[4][2];
#pragma unroll
        for (int t = 0; t < 4; ++t) {
            xA[t][0] = xf4[t * 8];
            xA[t][1] = xf4[t * 8 + 1];
        }

        // stage w (64x256 f32 -> bf16 LDS, stride 264)
#pragma unroll
        for (int i = 0; i < 16; ++i) {
            const int idx4 = i * 256 + tid;             // float4 index, < 4096
            const int r = idx4 >> 6, c4 = idx4 & 63;
            const float4 wv = ((const float4*)wsrc)[idx4];
            uint2 pk;
            pk.x = pack_bf16x2(wv.x, wv.y);
            pk.y = pack_bf16x2(wv.z, wv.w);
            *(uint2*)&wlds[r * 264 + c4 * 4] = pk;
        }
        __syncthreads();

        ffrag acc[4];
#pragma unroll
        for (int dt = 0; dt < 4; ++dt) acc[dt] = (ffrag)(0.0f);

        float4 xB[4][2];
#pragma unroll
        for (int kf = 0; kf < 4; ++kf) {
            xB[kf][0] = xf4[(kf + 4) * 8];
            xB[kf][1] = xf4[(kf + 4) * 8 + 1];
            proj_step(xA[kf][0], xA[kf][1], wlds, kf, m, quad, acc);
        }
#pragma unroll
        for (int kf = 0; kf < 4; ++kf)
            proj_step(xB[kf][0], xB[kf][1], wlds, kf + 4, m, quad, acc);

#pragma unroll
        for (int dt = 0; dt < 4; ++dt)
#pragma unroll
            for (int r = 0; r < 4; ++r)
                o[(rows0 + quad * 4 + r) * DK + dt * 16 + m] =
                    f2bf(fmaxf(acc[dt][r], 0.0f) * scale);
    }
}

// ---------------------------------------------------------------------------
// Attention. R7: arithmetic-intensity doubling against the per-CU L1 wall.
// 256 blocks x 512 threads (8 waves). Each block owns 64 query rows; wave w
// owns keys [w*512, w*512+512) = 16 tiles. Same K/V bytes per wave-tile now
// feed 2x the MFMA (4 mt-groups): per-CU L1 fill traffic per unit compute
// halves (512 MB -> 256 MB total). Waves/CU unchanged (8 = 2/SIMD at <=256
// VGPR via launch_bounds(512,2)). Ping-pong K/V, unroll 2, XCD swizzle kept.
// ---------------------------------------------------------------------------
__global__ __launch_bounds__(512, 2) void attn_mfma(
    const unsigned short* __restrict__ qp, const unsigned short* __restrict__ kp,
    const unsigned short* __restrict__ vT, float* __restrict__ out)
{
    __shared__ __align__(16) char smem[40960];   // P: 8 waves x 5120B; epilogue reuse
    unsigned short* Plds = (unsigned short*)smem;

    const int tid  = threadIdx.x;
    const int lane = tid & 63, w = tid >> 6;     // w in 0..7
    const int m = lane & 15, quad = lane >> 4;

    // XCD-chunked bijective remap (256 % 8 == 0, chunk = 32)
    const int flat = blockIdx.x;                 // 0..255
    const int qg   = ((flat & 7) << 5) | (flat >> 3);   // 0..255 (64-row groups)

    const int qbase = qg * 64;
    const int b = qg >> 6;
    const int kstart = w * 512;                  // 16 tiles of 32 keys / wave

    bfrag qa[4][2];
#pragma unroll
    for (int mt = 0; mt < 4; ++mt)
#pragma unroll
        for (int kf = 0; kf < 2; ++kf)
            qa[mt][kf] = *(const bfrag*)&qp[(qbase + mt * 16 + m) * DK + kf * 32 + quad * 8];

    ffrag oacc[4][4];
    float dacc[4][4];
#pragma unroll
    for (int mt = 0; mt < 4; ++mt) {
#pragma unroll
        for (int dt = 0; dt < 4; ++dt) oacc[mt][dt] = (ffrag)(0.0f);
#pragma unroll
        for (int r = 0; r < 4; ++r) dacc[mt][r] = 0.0f;
    }

    // stepped base pointers; per-tile offsets are imm-able
    const unsigned short* kptr = kp + ((size_t)b * S_ + kstart + m) * DK + quad * 8;
    const unsigned short* vptr = vT + ((size_t)(b * 128 + (kstart >> 5)) * 64 + m) * 32 + quad * 8;
    unsigned short* Pw = Plds + w * 2560;        // 5120 B per wave: [64][40]

    const ffrag cbias = (ffrag)(PACK_BIAS);

    // preload tile 0 into slot 0
    bfrag kbuf[2][2][2], vbuf[2][4];
#pragma unroll
    for (int kt = 0; kt < 2; ++kt)
#pragma unroll
        for (int kf = 0; kf < 2; ++kf)
            kbuf[0][kt][kf] = *(const bfrag*)(kptr + kt * 1024 + kf * 32);
#pragma unroll
    for (int dt = 0; dt < 4; ++dt)
        vbuf[0][dt] = *(const bfrag*)(vptr + dt * 512);

    bfrag pa0, pa1, pa2, pa3;

#pragma unroll 2
    for (int jj = 0; jj < 16; ++jj) {
        const int p = jj & 1;

        // 1) prefetch K(jj+1) -> kbuf[p^1]
        if (jj < 15) {
            const unsigned short* kn = kptr + (jj + 1) * 2048;
#pragma unroll
            for (int kt = 0; kt < 2; ++kt)
#pragma unroll
                for (int kf = 0; kf < 2; ++kf)
                    kbuf[p ^ 1][kt][kf] = *(const bfrag*)(kn + kt * 1024 + kf * 32);
        }

        // 2) PV(jj-1): pa x V(jj-1) in vbuf[p^1] (dies here)
        if (jj > 0) {
#pragma unroll
            for (int dt = 0; dt < 4; ++dt) {
                oacc[0][dt] = __builtin_amdgcn_mfma_f32_16x16x32_bf16(pa0, vbuf[p ^ 1][dt], oacc[0][dt], 0, 0, 0);
                oacc[1][dt] = __builtin_amdgcn_mfma_f32_16x16x32_bf16(pa1, vbuf[p ^ 1][dt], oacc[1][dt], 0, 0, 0);
                oacc[2][dt] = __builtin_amdgcn_mfma_f32_16x16x32_bf16(pa2, vbuf[p ^ 1][dt], oacc[2][dt], 0, 0, 0);
                oacc[3][dt] = __builtin_amdgcn_mfma_f32_16x16x32_bf16(pa3, vbuf[p ^ 1][dt], oacc[3][dt], 0, 0, 0);
            }
        }

        // 3) prefetch V(jj+1) -> vbuf[p^1] (slot just freed)
        if (jj < 15) {
            const unsigned short* vn = vptr + (jj + 1) * 2048;
#pragma unroll
            for (int dt = 0; dt < 4; ++dt)
                vbuf[p ^ 1][dt] = *(const bfrag*)(vn + dt * 512);
        }

        const bool mask0 = (jj == 0) && (w == 0) && (m == 0);

        // 4a) QK(jj) mt 0-1 on kbuf[p]; exp + den + pack -> LDS
        {
            ffrag s[2][2];
#pragma unroll
            for (int mt = 0; mt < 2; ++mt)
#pragma unroll
                for (int kt = 0; kt < 2; ++kt) {
                    ffrag t = __builtin_amdgcn_mfma_f32_16x16x32_bf16(qa[mt][0], kbuf[p][kt][0], cbias, 0, 0, 0);
                    s[mt][kt] = __builtin_amdgcn_mfma_f32_16x16x32_bf16(qa[mt][1], kbuf[p][kt][1], t, 0, 0, 0);
                }
#pragma unroll
            for (int mt = 0; mt < 2; ++mt)
#pragma unroll
                for (int r = 0; r < 4; ++r) {
                    float e0 = fast_exp2(s[mt][0][r]);
                    float e1 = fast_exp2(s[mt][1][r]);
                    if (mask0) e0 = 0.0f;
                    dacc[mt][r] += e0 + e1;
                    *(unsigned*)&Pw[(mt * 16 + quad * 4 + r) * 40 + m * 2] =
                        trunc_pack_bf16x2(e0, e1);
                }
        }
        // 4b) QK(jj) mt 2-3; exp + den + pack -> LDS
        {
            ffrag s[2][2];
#pragma unroll
            for (int mt = 2; mt < 4; ++mt)
#pragma unroll
                for (int kt = 0; kt < 2; ++kt) {
                    ffrag t = __builtin_amdgcn_mfma_f32_16x16x32_bf16(qa[mt][0], kbuf[p][kt][0], cbias, 0, 0, 0);
                    s[mt - 2][kt] = __builtin_amdgcn_mfma_f32_16x16x32_bf16(qa[mt][1], kbuf[p][kt][1], t, 0, 0, 0);
                }
#pragma unroll
            for (int mt = 2; mt < 4; ++mt)
#pragma unroll
                for (int r = 0; r < 4; ++r) {
                    float e0 = fast_exp2(s[mt - 2][0][r]);
                    float e1 = fast_exp2(s[mt - 2][1][r]);
                    if (mask0) e0 = 0.0f;
                    dacc[mt][r] += e0 + e1;
                    *(unsigned*)&Pw[(mt * 16 + quad * 4 + r) * 40 + m * 2] =
                        trunc_pack_bf16x2(e0, e1);
                }
        }

        // 5) read P(jj) as A-frags (per-wave DS in-order)
        pa0 = *(const bfrag*)&Pw[(m) * 40 + quad * 8];
        pa1 = *(const bfrag*)&Pw[(16 + m) * 40 + quad * 8];
        pa2 = *(const bfrag*)&Pw[(32 + m) * 40 + quad * 8];
        pa3 = *(const bfrag*)&Pw[(48 + m) * 40 + quad * 8];
    }
    // final PV (tile 15): V(15) is in vbuf[1] (loop count even)
#pragma unroll
    for (int dt = 0; dt < 4; ++dt) {
        oacc[0][dt] = __builtin_amdgcn_mfma_f32_16x16x32_bf16(pa0, vbuf[1][dt], oacc[0][dt], 0, 0, 0);
        oacc[1][dt] = __builtin_amdgcn_mfma_f32_16x16x32_bf16(pa1, vbuf[1][dt], oacc[1][dt], 0, 0, 0);
        oacc[2][dt] = __builtin_amdgcn_mfma_f32_16x16x32_bf16(pa2, vbuf[1][dt], oacc[2][dt], 0, 0, 0);
        oacc[3][dt] = __builtin_amdgcn_mfma_f32_16x16x32_bf16(pa3, vbuf[1][dt], oacc[3][dt], 0, 0, 0);
    }

    // den: reduce over the 16 key-lanes within each quad group
#pragma unroll
    for (int mt = 0; mt < 4; ++mt)
#pragma unroll
        for (int r = 0; r < 4; ++r) {
            float d = dacc[mt][r];
            d += __shfl_xor(d, 1, 64);
            d += __shfl_xor(d, 2, 64);
            d += __shfl_xor(d, 4, 64);
            d += __shfl_xor(d, 8, 64);
            dacc[mt][r] = d;
        }

    // 8-wave tree reduce, two mt-halves (chunk = 2560 f32/wave; 4 chunks
    // fit the 40 KB smem). P is dead.
    float* red = (float*)smem;                   // red_i = red + i*2560
#pragma unroll
    for (int half = 0; half < 2; ++half) {
        const int mt0 = half * 2;
        __syncthreads();
        if (w >= 4) {
            float* dst = red + (w - 4) * 2560;
#pragma unroll
            for (int mr = 0; mr < 2; ++mr) {
#pragma unroll
                for (int dt = 0; dt < 4; ++dt)
#pragma unroll
                    for (int r = 0; r < 4; ++r)
                        dst[((mr * 4 + dt) * 4 + r) * 64 + lane] = oacc[mt0 + mr][dt][r];
#pragma unroll
                for (int r = 0; r < 4; ++r)
                    dst[2048 + (mr * 4 + r) * 64 + lane] = dacc[mt0 + mr][r];
            }
        }
        __syncthreads();
        if (w < 4) {
            const float* src = red + w * 2560;
#pragma unroll
            for (int mr = 0; mr < 2; ++mr) {
#pragma unroll
                for (int dt = 0; dt < 4; ++dt)
#pragma unroll
                    for (int r = 0; r < 4; ++r)
                        oacc[mt0 + mr][dt][r] += src[((mr * 4 + dt) * 4 + r) * 64 + lane];
#pragma unroll
                for (int r = 0; r < 4; ++r)
                    dacc[mt0 + mr][r] += src[2048 + (mr * 4 + r) * 64 + lane];
            }
        }
        __syncthreads();
        if (w >= 2 && w < 4) {
            float* dst = red + (w - 2) * 2560;
#pragma unroll
            for (int mr = 0; mr < 2; ++mr) {
#pragma unroll
                for (int dt = 0; dt < 4; ++dt)
#pragma unroll
                    for (int r = 0; r < 4; ++r)
                        dst[((mr * 4 + dt) * 4 + r) * 64 + lane] = oacc[mt0 + mr][dt][r];
#pragma unroll
                for (int r = 0; r < 4; ++r)
                    dst[2048 + (mr * 4 + r) * 64 + lane] = dacc[mt0 + mr][r];
            }
        }
        __syncthreads();
        if (w < 2) {
            const float* src = red + w * 2560;
#pragma unroll
            for (int mr = 0; mr < 2; ++mr) {
#pragma unroll
                for (int dt = 0; dt < 4; ++dt)
#pragma unroll
                    for (int r = 0; r < 4; ++r)
                        oacc[mt0 + mr][dt][r] += src[((mr * 4 + dt) * 4 + r) * 64 + lane];
#pragma unroll
                for (int r = 0; r < 4; ++r)
                    dacc[mt0 + mr][r] += src[2048 + (mr * 4 + r) * 64 + lane];
            }
        }
        __syncthreads();
        if (w == 1) {
#pragma unroll
            for (int mr = 0; mr < 2; ++mr) {
#pragma unroll
                for (int dt = 0; dt < 4; ++dt)
#pragma unroll
                    for (int r = 0; r < 4; ++r)
                        red[((mr * 4 + dt) * 4 + r) * 64 + lane] = oacc[mt0 + mr][dt][r];
#pragma unroll
                for (int r = 0; r < 4; ++r)
                    red[2048 + (mr * 4 + r) * 64 + lane] = dacc[mt0 + mr][r];
            }
        }
        __syncthreads();
        if (w == 0) {
#pragma unroll
            for (int mr = 0; mr < 2; ++mr) {
                const int mt = mt0 + mr;
                float invd[4];
#pragma unroll
                for (int r = 0; r < 4; ++r) {
                    const float dv = dacc[mt][r] + red[2048 + (mr * 4 + r) * 64 + lane];
                    invd[r] = 1.0f / dv;
                }
#pragma unroll
                for (int dt = 0; dt < 4; ++dt)
#pragma unroll
                    for (int r = 0; r < 4; ++r) {
                        const float nv = oacc[mt][dt][r] + red[((mr * 4 + dt) * 4 + r) * 64 + lane];
                        out[(size_t)(qbase + mt * 16 + quad * 4 + r) * DK + dt * 16 + m] =
                            nv * invd[r];
                    }
            }
        }
    }
}

// ---------------------------------------------------------------------------
extern "C" void kernel_launch(void* const* d_in, const int* in_sizes, int n_in,
                              void* d_out, int out_size, void* d_ws, size_t ws_size,
                              hipStream_t stream)
{
    const float* q  = (const float*)d_in[0];
    const float* k  = (const float*)d_in[1];
    const float* v  = (const float*)d_in[2];
    const float* wq = (const float*)d_in[3];
    const float* wk = (const float*)d_in[4];
    float* out = (float*)d_out;

    // ws: qpb 2M | kpb 2M | vT 2M
    char* p = (char*)d_ws;
    unsigned short* qpb = (unsigned short*)p;   p += (size_t)NROWS * DK * 2;
    unsigned short* kpb = (unsigned short*)p;   p += (size_t)NROWS * DK * 2;
    unsigned short* vT  = (unsigned short*)p;

    fused_prep<<<768, 256, 0, stream>>>(q, k, v, wq, wk, vT, qpb, kpb);
    attn_mfma<<<256, 512, 0, stream>>>(qpb, kpb, vT, out);
}